// Round 8
// baseline (373.048 us; speedup 1.0000x reference)
//
#include <hip/hip_runtime.h>
#include <stdint.h>

#define TT 300
#define DD 40
#define SB 8                     // samples per block; grid 256
#define ABYTES (8 * 128 * 2)     // 2048 B per A buffer (8 rows x 128 f16)

typedef __attribute__((ext_vector_type(8))) _Float16 half8;
typedef __attribute__((ext_vector_type(4))) float f32x4;

// Barrier that does NOT drain vmcnt: LDS ops retired (lgkmcnt), global loads stay in flight.
__device__ __forceinline__ void bar() {
  asm volatile("s_waitcnt lgkmcnt(0)" ::: "memory");
  __builtin_amdgcn_s_barrier();
  asm volatile("" ::: "memory");
}

// Swizzled byte offset into the 8-row A tile: row-major [8][128] f16 with
// byte ^= row<<4. Rows are 256 B (≡0 mod 128) so the XOR stays inside the row
// and preserves 16B alignment for ds_read_b128.
__device__ __forceinline__ int aswz(int row, int colh) {
  return (row * 256 + colh * 2) ^ (row << 4);
}

// FP16 pipeline, K = 128 (4 ktiles of 32):
//   k  0..39 : x_t (f16)      k 40,41 : 1.0 -> bias hi/lo (f16 pair ~ 2^-23) folded in
//   k 42..63 : zero           k 64..127 : h_u (SINGLE f16, k = 64+u; W row 40+u)
// 8 waves, wave wv owns units 8wv..8wv+7 as 2 ntiles of 16 cols:
//   ntile nt, frag col n -> gate g = nt + 2*(n>>3), unit u = 8wv + (n&7)
// B-fragments loaded DIRECTLY from global (no LDS staging phase at all).
// A tile has 8 ROWS (row = sample); MFMA lanes 8..15 re-read row n&7 (broadcast);
// output rows 8..15 duplicate 0..7: lane (q,n) acc comp r = sample (q&1)*4 + r.
// Lane ownership: sample sl = (q&1)*4 + (q>>1)*2 + b, unit u = 8wv + (n&7).
// Gates: 2-shfl exchange with lane n^8 (it holds the other gate pair).
__global__ __launch_bounds__(512, 2) void lstm_mfma_kernel(
    const float* __restrict__ X, const int* __restrict__ seqlen,
    const float* __restrict__ Wk, const float* __restrict__ bias,
    float* __restrict__ hfin)
{
  __shared__ char Ab[2 * ABYTES];   // 4 KB total: A double-buffer only

  const int tid = threadIdx.x;
  const int wv = tid >> 6, lane = tid & 63;
  const int q = lane >> 4, n = lane & 15, m = n & 7, b = n >> 3;
  const int s0 = blockIdx.x * SB;

  // ---- zero both A buffers ----
  for (int i = tid; i < 2 * ABYTES / 4; i += 512)
    reinterpret_cast<uint32_t*>(Ab)[i] = 0;

  // ---- B fragments straight from global (8 frags = 32 VGPRs/wave) ----
  // B[k][n] frag layout: col = n, k = kt*32 + q*8 + j
  half8 Bf[4][2];
  #pragma unroll
  for (int nt = 0; nt < 2; ++nt) {
    const int g = nt + 2 * b;
    const int col = g * 64 + 8 * wv + m;
    const float bv = bias[col] + ((g == 2) ? 1.0f : 0.0f);   // forget-gate +1
    const _Float16 bhi = (_Float16)bv;
    const _Float16 blo = (_Float16)(bv - (float)bhi);
    #pragma unroll
    for (int kt = 0; kt < 4; ++kt) {
      half8 f;
      #pragma unroll
      for (int j = 0; j < 8; ++j) {
        const int k = kt * 32 + q * 8 + j;
        _Float16 v = (_Float16)0.f;
        if (k < 40)       v = (_Float16)Wk[k * 256 + col];          // x weights
        else if (k == 40) v = bhi;
        else if (k == 41) v = blo;
        else if (k >= 64) v = (_Float16)Wk[(k - 24) * 256 + col];   // h weights (row 40+u)
        f[j] = v;
      }
      Bf[kt][nt] = f;
    }
  }

  // ---- per-lane ownership: ONE (sample, unit) pair ----
  const int hi2 = q >> 1;
  const int u = wv * 8 + m;
  const int sl = (q & 1) * 4 + hi2 * 2 + b;
  const int len = seqlen[s0 + sl];
  int ml = seqlen[s0 + (lane & 7)];      // block-max seqlen
  #pragma unroll
  for (int off = 1; off < 8; off <<= 1) ml = max(ml, __shfl_xor(ml, off));

  // x prefetch: 320 values/step; threads 0..319 own one (sample, dim) slot; row = sample
  const bool hasX = (tid < SB * DD);
  const int sA = (tid * 205) >> 13, dA = tid - sA * 40;   // exact for tid<320
  const float* pA = X + (size_t)(s0 + sA) * (TT * DD) + dA;
  const int xb = aswz(sA, dA);

  __syncthreads();                       // zeros visible before ones/x0 writes
  if (tid < 16) {   // ones at k=40,41 for all 8 rows, BOTH buffers (f16 1.0 = 0x3C00)
    int s = tid & 7, bb = tid >> 3;
    *reinterpret_cast<uint32_t*>(Ab + bb * ABYTES + aswz(s, 40)) = 0x3C003C00u;
  }
  float xvl = 0.f;                       // x(t+1), consumed at step t
  if (hasX) {
    *reinterpret_cast<_Float16*>(Ab + xb) = (_Float16)pA[0];   // x_0 into buffer 0
    if (ml > 1) xvl = pA[DD];
  }
  __syncthreads();
  pA += 2 * DD;                          // points at x(t+2) for t=0

  // A-frag swizzled byte offsets (loop-invariant): row = n&7 (lanes 8..15 duplicate)
  int aoff[4];
  #pragma unroll
  for (int kt = 0; kt < 4; ++kt)
    aoff[kt] = (m * 256 + kt * 64 + q * 16) ^ (m << 4);

  float cst = 0.f, hf = 0.f;
  const int hb = aswz(sl, 64 + u);       // my (sample,unit) h slot (f16, 2B)
  const f32x4 zero4 = {0.f, 0.f, 0.f, 0.f};

  auto STEP = [&](int t, int RB, int WB) {
    half8 A0 = *reinterpret_cast<const half8*>(Ab + RB + aoff[0]);
    half8 A1 = *reinterpret_cast<const half8*>(Ab + RB + aoff[1]);
    half8 A2 = *reinterpret_cast<const half8*>(Ab + RB + aoff[2]);
    half8 A3 = *reinterpret_cast<const half8*>(Ab + RB + aoff[3]);

    f32x4 ac0 = __builtin_amdgcn_mfma_f32_16x16x32_f16(A0, Bf[0][0], zero4, 0, 0, 0);
    f32x4 ac1 = __builtin_amdgcn_mfma_f32_16x16x32_f16(A0, Bf[0][1], zero4, 0, 0, 0);
    ac0 = __builtin_amdgcn_mfma_f32_16x16x32_f16(A1, Bf[1][0], ac0, 0, 0, 0);
    ac1 = __builtin_amdgcn_mfma_f32_16x16x32_f16(A1, Bf[1][1], ac1, 0, 0, 0);

    // publish x(t+1) (loaded last iteration) into the NEXT buffer; issue x(t+2) load
    if (hasX && t + 1 < ml) *reinterpret_cast<_Float16*>(Ab + WB + xb) = (_Float16)xvl;
    float xn = 0.f;
    if (hasX && t + 2 < ml) { xn = pA[0]; pA += DD; }

    ac0 = __builtin_amdgcn_mfma_f32_16x16x32_f16(A2, Bf[2][0], ac0, 0, 0, 0);
    ac1 = __builtin_amdgcn_mfma_f32_16x16x32_f16(A2, Bf[2][1], ac1, 0, 0, 0);
    ac0 = __builtin_amdgcn_mfma_f32_16x16x32_f16(A3, Bf[3][0], ac0, 0, 0, 0);
    ac1 = __builtin_amdgcn_mfma_f32_16x16x32_f16(A3, Bf[3][1], ac1, 0, 0, 0);

    // select my 2 components (samples base, base+1), exchange 2 values with lane n^8
    float v0_s0 = hi2 ? ac0[2] : ac0[0];
    float v0_s1 = hi2 ? ac0[3] : ac0[1];
    float v1_s0 = hi2 ? ac1[2] : ac1[0];
    float v1_s1 = hi2 ? ac1[3] : ac1[1];
    float own0 = b ? v0_s1 : v0_s0;      // gate 2b   of my sample
    float own1 = b ? v1_s1 : v1_s0;      // gate 2b+1 of my sample
    float snd0 = b ? v0_s0 : v0_s1;      // gate 2b   of partner's sample
    float snd1 = b ? v1_s0 : v1_s1;
    float rcv0 = __shfl_xor(snd0, 8);    // gate 2(1-b) of my sample
    float rcv1 = __shfl_xor(snd1, 8);
    float gi = b ? rcv0 : own0;
    float gj = b ? rcv1 : own1;
    float gf = b ? own0 : rcv0;
    float go = b ? own1 : rcv1;

    // sigm(i)*tanh(j) = (Ej-1)*rcp((1+Ei)(1+Ej)); tanh(nc)*sigm(o) likewise. Bias already in.
    float Ef = __expf(-gf), Ei = __expf(-gi), Ej = __expf(2.f * gj);
    float nc = fmaf(cst, __builtin_amdgcn_rcpf(1.f + Ef),
                    (Ej - 1.f) * __builtin_amdgcn_rcpf((1.f + Ei) * (1.f + Ej)));
    float En = __expf(2.f * fminf(nc, 44.f)), Eo = __expf(-go);
    float nh = (En - 1.f) * __builtin_amdgcn_rcpf((1.f + En) * (1.f + Eo));
    cst = nc;
    if (t == len - 1) hf = nh;

    // h feedback: SINGLE f16 (2^-12), one 2-byte write into the NEXT buffer
    *reinterpret_cast<_Float16*>(Ab + WB + hb) = (_Float16)nh;

    bar();   // single barrier/step: publishes buf[t+1], retires reads of buf[t]
    xvl = xn;
  };

  for (int t = 0; t < ml; ) {            // ml is block-uniform -> uniform branches
    STEP(t, 0, ABYTES); ++t;
    if (t >= ml) break;
    STEP(t, ABYTES, 0); ++t;
  }

  hfin[(size_t)(s0 + sl) * 64 + u] = hf;
}

// head: 16 samples per block (128 blocks) -> W2 read 128x instead of 2048x
__global__ __launch_bounds__(256, 1) void head_kernel(
    const float* __restrict__ hfin,
    const float* __restrict__ W1, const float* __restrict__ b1,
    const float* __restrict__ gamma, const float* __restrict__ beta,
    const float* __restrict__ mmean, const float* __restrict__ mvar,
    const float* __restrict__ W2, const float* __restrict__ b2,
    float* __restrict__ out)
{
  __shared__ float hl[16 * 64];     // 4 KB
  __shared__ float d1t[128 * 20];   // transposed d1 [k][s], stride 20 (16B-aligned)
  __shared__ float lg[16 * 516];    // 33 KB logits
  const int tid = threadIdx.x;
  const int b0 = blockIdx.x * 16;

  for (int i = tid; i < 16 * 64; i += 256) hl[i] = hfin[(size_t)b0 * 64 + i];
  __syncthreads();

  { // dense1 + BN + ReLU: thread = (col j, sample-group sg), 8 samples each
    const int j = tid & 127, sg = tid >> 7;
    float acc[8];
    const float bb = b1[j];
    #pragma unroll
    for (int s = 0; s < 8; ++s) acc[s] = bb;
    for (int k = 0; k < 64; ++k) {
      float w = W1[k * 128 + j];
      #pragma unroll
      for (int s = 0; s < 8; ++s) acc[s] = fmaf(hl[(sg * 8 + s) * 64 + k], w, acc[s]);
    }
    const float ga = gamma[j], be = beta[j], mm = mmean[j];
    const float iv = rsqrtf(mvar[j] + 1e-3f);
    #pragma unroll
    for (int s = 0; s < 8; ++s) {
      float v = fmaxf(acc[s], 0.f);
      d1t[j * 20 + sg * 8 + s] = ga * (v - mm) * iv + be;
    }
  }
  __syncthreads();

  { // logits: thread owns cols 2*tid, 2*tid+1 for all 16 samples
    const int cA = tid * 2;
    float accA[16], accB[16];
    const float bA = b2[cA], bB = b2[cA + 1];
    #pragma unroll
    for (int s = 0; s < 16; ++s) { accA[s] = bA; accB[s] = bB; }
    for (int k = 0; k < 128; ++k) {
      const float2 w = *reinterpret_cast<const float2*>(&W2[k * 512 + cA]);
      const f32x4 dq0 = *reinterpret_cast<const f32x4*>(&d1t[k * 20]);
      const f32x4 dq1 = *reinterpret_cast<const f32x4*>(&d1t[k * 20 + 4]);
      const f32x4 dq2 = *reinterpret_cast<const f32x4*>(&d1t[k * 20 + 8]);
      const f32x4 dq3 = *reinterpret_cast<const f32x4*>(&d1t[k * 20 + 12]);
      #pragma unroll
      for (int s = 0; s < 4; ++s) {
        accA[s]      = fmaf(dq0[s], w.x, accA[s]);      accB[s]      = fmaf(dq0[s], w.y, accB[s]);
        accA[s + 4]  = fmaf(dq1[s], w.x, accA[s + 4]);  accB[s + 4]  = fmaf(dq1[s], w.y, accB[s + 4]);
        accA[s + 8]  = fmaf(dq2[s], w.x, accA[s + 8]);  accB[s + 8]  = fmaf(dq2[s], w.y, accB[s + 8]);
        accA[s + 12] = fmaf(dq3[s], w.x, accA[s + 12]); accB[s + 12] = fmaf(dq3[s], w.y, accB[s + 12]);
      }
    }
    #pragma unroll
    for (int s = 0; s < 16; ++s) {
      lg[s * 516 + cA]     = accA[s];
      lg[s * 516 + cA + 1] = accB[s];
    }
  }
  __syncthreads();

  { // softmax: wave handles 4 samples, 8 cols/lane
    const int w = tid >> 6, lane = tid & 63;
    #pragma unroll
    for (int si = 0; si < 4; ++si) {
      const int s = w * 4 + si;
      float v[8];
      float mx = -3.4e38f;
      #pragma unroll
      for (int i = 0; i < 8; ++i) { v[i] = lg[s * 516 + lane + 64 * i]; mx = fmaxf(mx, v[i]); }
      #pragma unroll
      for (int off = 1; off < 64; off <<= 1) mx = fmaxf(mx, __shfl_xor(mx, off));
      float sum = 0.f;
      #pragma unroll
      for (int i = 0; i < 8; ++i) { v[i] = __expf(v[i] - mx); sum += v[i]; }
      #pragma unroll
      for (int off = 1; off < 64; off <<= 1) sum += __shfl_xor(sum, off);
      const float inv = __builtin_amdgcn_rcpf(sum);
      #pragma unroll
      for (int i = 0; i < 8; ++i)
        out[(size_t)(b0 + s) * 512 + lane + 64 * i] = v[i] * inv;
    }
  }
}

extern "C" void kernel_launch(void* const* d_in, const int* in_sizes, int n_in,
                              void* d_out, int out_size, void* d_ws, size_t ws_size,
                              hipStream_t stream) {
  const float* X      = (const float*)d_in[0];
  const int*   seqlen = (const int*)d_in[1];
  const float* Wk     = (const float*)d_in[2];
  const float* bias   = (const float*)d_in[3];
  const float* W1     = (const float*)d_in[4];
  const float* b1     = (const float*)d_in[5];
  const float* gam    = (const float*)d_in[6];
  const float* bet    = (const float*)d_in[7];
  const float* mmean  = (const float*)d_in[8];
  const float* mvar   = (const float*)d_in[9];
  const float* W2     = (const float*)d_in[10];
  const float* b2     = (const float*)d_in[11];
  float* out  = (float*)d_out;
  float* hfin = (float*)d_ws;   // 2048*64 fp32 = 512 KB

  lstm_mfma_kernel<<<dim3(2048 / SB), dim3(512), 0, stream>>>(X, seqlen, Wk, bias, hfin);
  head_kernel<<<dim3(128), dim3(256), 0, stream>>>(hfin, W1, b1, gam, bet,
                                                   mmean, mvar, W2, b2, out);
}